// Round 8
// baseline (56.166 us; speedup 1.0000x reference)
//
#include <hip/hip_runtime.h>
#include <math.h>

#define BB 256
#define NN 196
#define DD 768
#define TDK 32
#define NTILES (DD / TDK)   // 24
#define SROW 224            // tile row stride in floats: 896 B = 0 mod 32 banks
#define NITEMS (NN * 8)     // 1568 load-side items; also 32*49 store items

typedef float f32x4 __attribute__((ext_vector_type(4)));
typedef float f32x2 __attribute__((ext_vector_type(2)));

// Kernel 1: grid (BB, 2), 512 threads. Block (b,h) owns columns [98h, 98h+98).
// Rows split 8 ways across waves; lane l<49 owns 2 columns via float2 loads.
// Winner scatter: atomicMax(winner_g[b*196+pos], j+1) — global, max-commutative,
// deterministic; workspace memset to 0 before launch ("empty" = 0).
__global__ __launch_bounds__(512) void pos_conf_kernel(
    const float* __restrict__ logits,  // [B,N,N]
    float* __restrict__ conf_out,      // [B,N]
    int* __restrict__ winner_g)        // [B,N], zeroed
{
    const int b = blockIdx.x;
    const int h = blockIdx.y;
    const int t = threadIdx.x;
    const int wv = t >> 6;
    const int l  = t & 63;

    __shared__ float sm[8][98];
    __shared__ float ss[8][98];
    __shared__ int   si[8][98];

    const int i0 = (49 * wv) >> 1;            // (196*wv)/8
    const int i1 = (49 * (wv + 1)) >> 1;

    if (l < 49) {
        const float* basep = logits + (size_t)b * NN * NN + 98 * h + 2 * l;
        f32x2 m = {-INFINITY, -INFINITY};
        f32x2 s = {0.f, 0.f};
        int2 idx = make_int2(0, 0);
        #pragma unroll 4
        for (int i = i0; i < i1; ++i) {
            const f32x2 x = *reinterpret_cast<const f32x2*>(basep + (size_t)i * NN);
            f32x2 mn;
            mn.x = fmaxf(m.x, x.x);
            mn.y = fmaxf(m.y, x.y);
            idx.x = (x.x > m.x) ? i : idx.x;   // strict >: first occurrence
            idx.y = (x.y > m.y) ? i : idx.y;
            s.x = s.x * __expf(m.x - mn.x) + __expf(x.x - mn.x);
            s.y = s.y * __expf(m.y - mn.y) + __expf(x.y - mn.y);
            m = mn;
        }
        sm[wv][2 * l + 0] = m.x; ss[wv][2 * l + 0] = s.x; si[wv][2 * l + 0] = idx.x;
        sm[wv][2 * l + 1] = m.y; ss[wv][2 * l + 1] = s.y; si[wv][2 * l + 1] = idx.y;
    }
    __syncthreads();

    if (t < 98) {
        float m = -INFINITY;
        int idx = 0;
        #pragma unroll
        for (int w = 0; w < 8; ++w) {          // ascending rows: earliest chunk wins ties
            const float mg = sm[w][t];
            if (mg > m) { m = mg; idx = si[w][t]; }
        }
        float s = 0.f;
        #pragma unroll
        for (int w = 0; w < 8; ++w)
            s += ss[w][t] * __expf(sm[w][t] - m);
        const int j = 98 * h + t;
        conf_out[b * NN + j] = 1.0f / s;
        atomicMax(&winner_g[b * NN + idx], j + 1);   // later j wins; 0 = empty
    }
}

// Kernel 2: one 32-d tile per block, grid (24, BB), 256 threads, ONE barrier.
// XOR-swizzled LDS: element (d,p) at d*SROW + ((p>>2)^((d>>2)&7))*4 + (p&3).
__global__ __launch_bounds__(256) void rearrange_kernel(
    const float* __restrict__ features,  // [B,N,D]
    const int* __restrict__ winner_g,    // [B,N] (j+1 encoding)
    float* __restrict__ img)             // [B,D,N]
{
    const int kt = blockIdx.x;
    const int b  = blockIdx.y;
    const int t  = threadIdx.x;
    const int d0 = kt * TDK;

    __shared__ float tile[TDK * SROW];

    const float* fb = features + (size_t)b * NN * DD;
    const int* wb = winner_g + b * NN;

    // Prefetch winner codes (7 slots; slot 6 covers items 1536..1567).
    int wn[7], rr[7], k4[7];
    #pragma unroll
    for (int i = 0; i < 7; ++i) {
        const int item = t + 256 * i;
        rr[i] = item >> 3;
        k4[i] = (item & 7) * 4;
        wn[i] = (item < NITEMS) ? wb[rr[i]] : 0;
    }

    // Gather + swizzled transpose-write.
    #pragma unroll
    for (int i = 0; i < 7; ++i) {
        const int item = t + 256 * i;
        if (item < NITEMS) {
            f32x4 v = {0.f, 0.f, 0.f, 0.f};
            if (wn[i] > 0)
                v = *reinterpret_cast<const f32x4*>(fb + (size_t)(wn[i] - 1) * DD + d0 + k4[i]);
            const int r  = rr[i];
            const int kb = k4[i] >> 2;
            const int col = (((r >> 2) ^ kb) << 2) + (r & 3);
            tile[(k4[i] + 0) * SROW + col] = v.x;
            tile[(k4[i] + 1) * SROW + col] = v.y;
            tile[(k4[i] + 2) * SROW + col] = v.z;
            tile[(k4[i] + 3) * SROW + col] = v.w;
        }
    }
    __syncthreads();

    // Smooth + contiguous nontemporal stores: q -> (dl = q/49, c = q%49).
    float* ob = img + (size_t)b * DD * NN + (size_t)d0 * NN;
    #pragma unroll
    for (int it = 0; it < 7; ++it) {
        const int q = t + 256 * it;
        if (q < NITEMS) {
            const int dl  = q / 49;
            const int c   = q - 49 * dl;
            const int key = (dl >> 2) & 7;
            const float* row = &tile[dl * SROW];
            const f32x4 ctr = *reinterpret_cast<const f32x4*>(row + ((c ^ key) << 2));
            const float left  = (c > 0)  ? row[(((c - 1) ^ key) << 2) + 3] : 0.0f;
            const float right = (c < 48) ? row[ ((c + 1) ^ key) << 2      ] : 0.0f;
            const int p0 = 4 * c;
            f32x4 o;
            o.x = (p0 == 0)          ? ctr.x : (left  + ctr.x + ctr.y) * (1.0f / 3.0f);
            o.y = (ctr.x + ctr.y + ctr.z) * (1.0f / 3.0f);
            o.z = (ctr.y + ctr.z + ctr.w) * (1.0f / 3.0f);
            o.w = (p0 + 3 == NN - 1) ? ctr.w : (ctr.z + ctr.w + right) * (1.0f / 3.0f);
            __builtin_nontemporal_store(o, reinterpret_cast<f32x4*>(ob + (size_t)dl * NN + p0));
        }
    }
}

extern "C" void kernel_launch(void* const* d_in, const int* in_sizes, int n_in,
                              void* d_out, int out_size, void* d_ws, size_t ws_size,
                              hipStream_t stream) {
    const float* features = (const float*)d_in[0];
    const float* logits   = (const float*)d_in[1];

    float* out  = (float*)d_out;
    float* img  = out;                              // B*D*N floats
    float* conf = out + (size_t)BB * DD * NN;       // B*N floats
    int*   winner = (int*)d_ws;                     // B*N ints (j+1; 0 = empty)

    hipMemsetAsync(winner, 0, (size_t)BB * NN * sizeof(int), stream);

    dim3 g1(BB, 2);
    pos_conf_kernel<<<g1, 512, 0, stream>>>(logits, conf, winner);

    dim3 g2(NTILES, BB);
    rearrange_kernel<<<g2, 256, 0, stream>>>(features, winner, img);
}

// Round 9
// 50.492 us; speedup vs baseline: 1.1124x; 1.1124x over previous
//
#include <hip/hip_runtime.h>
#include <math.h>

#define BB 256
#define NN 196
#define DD 768
#define TDK 32
#define NTILES (DD / TDK)   // 24
#define SROW 224            // tile row stride in floats: 896 B = 0 mod 32 banks
#define NITEMS (NN * 8)     // 1568 items per tile (load side; also 32*49 store side)
#define NW 16               // waves per block

typedef float f32x4 __attribute__((ext_vector_type(4)));

// One block per batch, 1024 threads, ONE dispatch.
// Phase A: argmax + max-softmax over axis=1 (winner in LDS, no global round-trip).
// Phase B: 24 d-tiles, double-buffered XOR-swizzled LDS -> ONE barrier per tile.
// LDS overlay: phase-A arrays and phase-B tile buffers share storage (union).
__global__ __launch_bounds__(1024) void fused_kernel(
    const float* __restrict__ features,  // [B,N,D]
    const float* __restrict__ logits,    // [B,N,N]
    float* __restrict__ img,             // [B,D,N]
    float* __restrict__ conf_out)        // [B,N]
{
    const int b = blockIdx.x;
    const int t = threadIdx.x;

    __shared__ union {
        struct { float sm[NW][NN]; float ss[NW][NN]; int si[NW][NN]; } a;  // 37632 B
        float tiles[2][TDK * SROW];                                        // 57344 B
    } u;
    __shared__ int winner_s[NN];

    // ---------------- Phase A: pos + conf ----------------
    const int wv = t >> 6;
    const int l  = t & 63;

    if (t < NN) winner_s[t] = -1;

    {
        const int i0 = (49 * wv) >> 2;
        const int i1 = (49 * (wv + 1)) >> 2;
        if (l < 49) {
            const float* basep = logits + (size_t)b * NN * NN + 4 * l;
            f32x4 m = {-INFINITY, -INFINITY, -INFINITY, -INFINITY};
            f32x4 s = {0.f, 0.f, 0.f, 0.f};
            int4 idx = make_int4(0, 0, 0, 0);
            #pragma unroll 4
            for (int i = i0; i < i1; ++i) {
                const f32x4 x = *reinterpret_cast<const f32x4*>(basep + (size_t)i * NN);
                f32x4 mn;
                mn.x = fmaxf(m.x, x.x); mn.y = fmaxf(m.y, x.y);
                mn.z = fmaxf(m.z, x.z); mn.w = fmaxf(m.w, x.w);
                idx.x = (x.x > m.x) ? i : idx.x;   // strict >: first occurrence
                idx.y = (x.y > m.y) ? i : idx.y;
                idx.z = (x.z > m.z) ? i : idx.z;
                idx.w = (x.w > m.w) ? i : idx.w;
                s.x = s.x * __expf(m.x - mn.x) + __expf(x.x - mn.x);
                s.y = s.y * __expf(m.y - mn.y) + __expf(x.y - mn.y);
                s.z = s.z * __expf(m.z - mn.z) + __expf(x.z - mn.z);
                s.w = s.w * __expf(m.w - mn.w) + __expf(x.w - mn.w);
                m = mn;
            }
            const int c = 4 * l;
            u.a.sm[wv][c + 0] = m.x; u.a.ss[wv][c + 0] = s.x; u.a.si[wv][c + 0] = idx.x;
            u.a.sm[wv][c + 1] = m.y; u.a.ss[wv][c + 1] = s.y; u.a.si[wv][c + 1] = idx.y;
            u.a.sm[wv][c + 2] = m.z; u.a.ss[wv][c + 2] = s.z; u.a.si[wv][c + 2] = idx.z;
            u.a.sm[wv][c + 3] = m.w; u.a.ss[wv][c + 3] = s.w; u.a.si[wv][c + 3] = idx.w;
        }
    }
    __syncthreads();

    if (t < NN) {
        const int j = t;
        float m = -INFINITY;
        int idx = 0;
        #pragma unroll
        for (int ww = 0; ww < NW; ++ww) {    // ascending rows: earliest chunk wins ties
            const float mg = u.a.sm[ww][j];
            if (mg > m) { m = mg; idx = u.a.si[ww][j]; }
        }
        float s = 0.0f;
        #pragma unroll
        for (int ww = 0; ww < NW; ++ww)
            s += u.a.ss[ww][j] * __expf(u.a.sm[ww][j] - m);
        conf_out[b * NN + j] = 1.0f / s;
        atomicMax(&winner_s[idx], j);        // winner[p] = max j with pos[j]==p
    }
    __syncthreads();                         // winner ready; phase-A arrays dead

    // ---------------- Phase B: gather + smooth + transpose-store ----------------
    const float* fb = features + (size_t)b * NN * DD;
    float* ob = img + (size_t)b * DD * NN;

    // Load-side items: item = r*8 + k; slot0 = t (always active), slot1 = t+1024.
    const int  r0  = t >> 3;
    const int  k40 = (t & 7) * 4;
    const bool a1  = (t + 1024) < NITEMS;    // t < 544
    const int  r1  = (t + 1024) >> 3;
    const int  k41 = ((t + 1024) & 7) * 4;

    const int w0 = winner_s[r0];
    const int w1 = a1 ? winner_s[r1] : -1;

    // Precomputed swizzled write columns (element (d,p): d*SROW + ((p>>2)^(d>>2&7))*4 + (p&3)).
    const int col0 = (((r0 >> 2) ^ (k40 >> 2)) << 2) + (r0 & 3);
    const int col1 = (((r1 >> 2) ^ (k41 >> 2)) << 2) + (r1 & 3);

    const f32x4 zero = {0.f, 0.f, 0.f, 0.f};
    f32x4 cur0, cur1, nxt0, nxt1;
    cur0 = (w0 >= 0) ? *reinterpret_cast<const f32x4*>(fb + (size_t)w0 * DD + k40) : zero;
    cur1 = (w1 >= 0) ? *reinterpret_cast<const f32x4*>(fb + (size_t)w1 * DD + k41) : zero;

    for (int kt = 0; kt < NTILES; ++kt) {
        float* buf = u.tiles[kt & 1];

        // Swizzled transpose-write of current tile into buf[kt&1].
        buf[(k40 + 0) * SROW + col0] = cur0.x;
        buf[(k40 + 1) * SROW + col0] = cur0.y;
        buf[(k40 + 2) * SROW + col0] = cur0.z;
        buf[(k40 + 3) * SROW + col0] = cur0.w;
        if (a1) {
            buf[(k41 + 0) * SROW + col1] = cur1.x;
            buf[(k41 + 1) * SROW + col1] = cur1.y;
            buf[(k41 + 2) * SROW + col1] = cur1.z;
            buf[(k41 + 3) * SROW + col1] = cur1.w;
        }

        // Prefetch next tile (in flight across the barrier region with the stores).
        nxt0 = zero; nxt1 = zero;
        if (kt + 1 < NTILES) {
            const int dn = (kt + 1) * TDK;
            if (w0 >= 0) nxt0 = *reinterpret_cast<const f32x4*>(fb + (size_t)w0 * DD + dn + k40);
            if (w1 >= 0) nxt1 = *reinterpret_cast<const f32x4*>(fb + (size_t)w1 * DD + dn + k41);
        }

        __syncthreads();                     // ONE barrier per tile

        // Smooth + contiguous nontemporal stores: q -> (dl = q/49, c = q%49).
        const int dg0 = kt * TDK;
        #pragma unroll
        for (int it = 0; it < 2; ++it) {
            const int q = t + 1024 * it;
            if (q < NITEMS) {
                const int dl  = q / 49;
                const int c   = q - 49 * dl;
                const int key = (dl >> 2) & 7;
                const float* row = &buf[dl * SROW];
                const f32x4 ctr = *reinterpret_cast<const f32x4*>(row + ((c ^ key) << 2));
                const float left  = (c > 0)  ? row[(((c - 1) ^ key) << 2) + 3] : 0.0f;
                const float right = (c < 48) ? row[ ((c + 1) ^ key) << 2      ] : 0.0f;
                const int p0 = 4 * c;
                f32x4 o;
                o.x = (p0 == 0)          ? ctr.x : (left  + ctr.x + ctr.y) * (1.0f / 3.0f);
                o.y = (ctr.x + ctr.y + ctr.z) * (1.0f / 3.0f);
                o.z = (ctr.y + ctr.z + ctr.w) * (1.0f / 3.0f);
                o.w = (p0 + 3 == NN - 1) ? ctr.w : (ctr.z + ctr.w + right) * (1.0f / 3.0f);
                __builtin_nontemporal_store(o, reinterpret_cast<f32x4*>(ob + (size_t)(dg0 + dl) * NN + p0));
            }
        }
        cur0 = nxt0; cur1 = nxt1;
        // no second barrier: next iteration writes the OTHER buffer; the next
        // __syncthreads separates this iteration's reads from the write-after
        // that reuses this buffer (two iterations later).
    }
}

extern "C" void kernel_launch(void* const* d_in, const int* in_sizes, int n_in,
                              void* d_out, int out_size, void* d_ws, size_t ws_size,
                              hipStream_t stream) {
    const float* features = (const float*)d_in[0];
    const float* logits   = (const float*)d_in[1];

    float* out  = (float*)d_out;
    float* img  = out;                              // B*D*N floats
    float* conf = out + (size_t)BB * DD * NN;       // B*N floats

    fused_kernel<<<BB, 1024, 0, stream>>>(features, logits, img, conf);
}